// Round 7
// baseline (371.557 us; speedup 1.0000x reference)
//
#include <hip/hip_runtime.h>

using f16   = _Float16;
using f16x4 = __attribute__((ext_vector_type(4))) _Float16;
using f16x8 = __attribute__((ext_vector_type(8))) _Float16;
using f32x4 = __attribute__((ext_vector_type(4))) float;

#define DEVI __device__ __forceinline__

namespace {
// 32KB LDS, two 16KB regions, time-multiplexed (wave-private sub-slots):
//  R_A: Xq -> Q (own cols) -> Xv -> V^T [128][64] (own rows)
//  R_B: Xk -> K (own cols) -> P halves (own 64B/row slot, halves time-share) -> O (own cols)
constexpr int R_A = 0;
constexpr int R_B = 16384;
constexpr float LOGIT_MAX_C = 4.6051701859880914f;  // log(100)
constexpr float L2E = 1.4426950408889634f;
}

// Bijective per-row XOR swizzle: conflict-free ds ops; per-row bijectivity
// preserves wave-private byte ownership (XOR with row-constant is injective).
DEVI int swzA(int row, int b) { return (row << 8) + (b ^ ((row & 7) << 4)); }  // 256B rows

DEVI f16x8 ldA(const char* base, int row, int k0) {   // [*,128] f16 tile, b128
  return *reinterpret_cast<const f16x8*>(base + swzA(row, k0 << 1));
}

// Stage one 64x128 fp32 tile -> f16 swizzled LDS tile (coalesced float4 loads)
DEVI void stage_in(const float* __restrict__ src, char* __restrict__ dst, int tid) {
#pragma unroll
  for (int i = 0; i < 8; ++i) {
    int f = tid + (i << 8);
    float4 v = reinterpret_cast<const float4*>(src)[f];
    f16x4 h;
    h[0] = (f16)v.x; h[1] = (f16)v.y; h[2] = (f16)v.z; h[3] = (f16)v.w;
    *reinterpret_cast<f16x4*>(dst + swzA(f >> 5, (f & 31) << 3)) = h;
  }
}

// X(lds) @ W^T accumulate (W fragments loaded per-kt: only 8 VGPR of W live).
DEVI void proj_acc(const char* __restrict__ xb, const f16* __restrict__ Wm,
                   f32x4 (&acc)[4][2], int w, int lr, int lg) {
#pragma unroll
  for (int mt = 0; mt < 4; ++mt)
#pragma unroll
    for (int n = 0; n < 2; ++n)
      acc[mt][n] = f32x4{0.f, 0.f, 0.f, 0.f};
#pragma unroll
  for (int kt = 0; kt < 4; ++kt) {
    f16x8 b0 = *reinterpret_cast<const f16x8*>(Wm + (w * 32 + lr) * 128 + kt * 32 + lg * 8);
    f16x8 b1 = *reinterpret_cast<const f16x8*>(Wm + (w * 32 + 16 + lr) * 128 + kt * 32 + lg * 8);
#pragma unroll
    for (int mt = 0; mt < 4; ++mt) {
      f16x8 a = ldA(xb, mt * 16 + lr, kt * 32 + lg * 8);
      acc[mt][0] = __builtin_amdgcn_mfma_f32_16x16x32_f16(a, b0, acc[mt][0], 0, 0, 0);
      acc[mt][1] = __builtin_amdgcn_mfma_f32_16x16x32_f16(a, b1, acc[mt][1], 0, 0, 0);
    }
  }
}

// C/D (col=lane&15, row=(lane>>4)*4+r) -> row-major [64][128] f16, own cols.
DEVI void epi_rowmajor(const f32x4 (&acc)[4][2], char* __restrict__ dst,
                       const float* __restrict__ bias, int w, int lr, int lg) {
  float b0 = bias ? bias[w * 32 + lr] : 0.f;
  float b1 = bias ? bias[w * 32 + 16 + lr] : 0.f;
#pragma unroll
  for (int mt = 0; mt < 4; ++mt)
#pragma unroll
    for (int n = 0; n < 2; ++n)
#pragma unroll
      for (int r = 0; r < 4; ++r) {
        int row = mt * 16 + lg * 4 + r;
        int col = w * 32 + n * 16 + lr;
        *reinterpret_cast<f16*>(dst + swzA(row, col << 1)) =
            (f16)(acc[mt][n][r] + (n ? b1 : b0));
      }
}

// fp32 weights -> f16 workspace (Wq,Wk,Wv,Wp)
__global__ void wcvt_kernel(const float* __restrict__ Wq, const float* __restrict__ Wk,
                            const float* __restrict__ Wv, const float* __restrict__ Wp,
                            f16* __restrict__ W16) {
  int idx = blockIdx.x * 256 + threadIdx.x;   // 0..16383
  int m = idx >> 12;
  int off = (idx & 4095) << 2;
  const float* src = m == 0 ? Wq : m == 1 ? Wk : m == 2 ? Wv : Wp;
  float4 v = *reinterpret_cast<const float4*>(src + off);
  f16x4 h;
  h[0] = (f16)v.x; h[1] = (f16)v.y; h[2] = (f16)v.z; h[3] = (f16)v.w;
  *reinterpret_cast<f16x4*>(W16 + (m << 14) + off) = h;
}

__global__ __launch_bounds__(256, 5)
void fpca_kernel(const float* __restrict__ q_in, const float* __restrict__ k_in,
                 const float* __restrict__ v_in, const float* __restrict__ pos_in,
                 const f16* __restrict__ W16,
                 const float* __restrict__ bq, const float* __restrict__ bv,
                 const float* __restrict__ bp, const float* __restrict__ lsc,
                 float* __restrict__ d_x, float* __restrict__ d_attn) {
  __shared__ char smem[32768];
  const int tid = threadIdx.x;
  const int w = tid >> 6;        // wave id == head id
  const int lane = tid & 63;
  const int lr = lane & 15;
  const int lg = lane >> 4;
  const int win = blockIdx.x;
  const int b = win >> 8;
  const size_t winOff = (size_t)win << 13;
  const f16* Wq16 = W16;
  const f16* Wk16 = W16 + 16384;
  const f16* Wv16 = W16 + 32768;
  const f16* Wp16 = W16 + 49152;

  // ---- ph1: stage Xq->A, Xk->B; prefetch Xv into f16 regs (issued early) ----
  stage_in(q_in + winOff, smem + R_A, tid);
  stage_in(k_in + winOff, smem + R_B, tid);
  const float4* vsrc = reinterpret_cast<const float4*>(v_in + winOff);
  f16x4 pfh[8];
#pragma unroll
  for (int i = 0; i < 8; ++i) {
    float4 v = vsrc[tid + (i << 8)];
    pfh[i][0] = (f16)v.x; pfh[i][1] = (f16)v.y;
    pfh[i][2] = (f16)v.z; pfh[i][3] = (f16)v.w;
  }
  __syncthreads();  // BAR1

  // ---- ph2: Q projection (reads all A) ----
  f32x4 accQ[4][2];
  proj_acc(smem + R_A, Wq16, accQ, w, lr, lg);
  __syncthreads();  // BAR2: all A reads done

  // ---- ph3: epi Q->A own cols; hoist bQ; K projection (reads all B) ----
  epi_rowmajor(accQ, smem + R_A, bq, w, lr, lg);
  f16x8 bQ[4];
#pragma unroll
  for (int nt = 0; nt < 4; ++nt)
    bQ[nt] = ldA(smem + R_A, nt * 16 + lr, w * 32 + lg * 8);
  f32x4 accK[4][2];
  proj_acc(smem + R_B, Wk16, accK, w, lr, lg);
  __syncthreads();  // BAR3: all B reads + all bQ hoists done

  // ---- ph4: Xv regs->A; epi K->B own; S^T+softmax in two nt-halves ----
#pragma unroll
  for (int i = 0; i < 8; ++i) {
    int f = tid + (i << 8);
    *reinterpret_cast<f16x4*>(smem + R_A + swzA(f >> 5, (f & 31) << 3)) = pfh[i];
  }
  epi_rowmajor(accK, smem + R_B, nullptr, w, lr, lg);
  const float scale = exp2f(fminf(lsc[w], LOGIT_MAX_C) * L2E);
  const float* pos = pos_in + (((size_t)b * 4 + w) << 12);
  float* attn_out = d_attn + (((size_t)win * 4 + w) << 12);
  f16x4 P16[4][4];   // packed P, written to LDS in ph6
#pragma unroll
  for (int h = 0; h < 2; ++h) {   // nt-half: nt = 2h, 2h+1  (s is 32 VGPRs)
    f32x4 s[4][2];
#pragma unroll
    for (int mt = 0; mt < 4; ++mt)
#pragma unroll
      for (int j = 0; j < 2; ++j)
        s[mt][j] = f32x4{0.f, 0.f, 0.f, 0.f};
#pragma unroll
    for (int mt = 0; mt < 4; ++mt) {
      f16x8 aK = ldA(smem + R_B, mt * 16 + lr, w * 32 + lg * 8);  // re-read per half
#pragma unroll
      for (int j = 0; j < 2; ++j)
        s[mt][j] = __builtin_amdgcn_mfma_f32_16x16x32_f16(aK, bQ[2 * h + j], s[mt][j], 0, 0, 0);
    }
#pragma unroll
    for (int j = 0; j < 2; ++j) {
      const int nt = 2 * h + j;
      const int q = nt * 16 + lr;   // lane's q-col; k = mt*16 + lg*4 + r (lane-local)
#pragma unroll
      for (int mt = 0; mt < 4; ++mt) {
        float4 pv = *reinterpret_cast<const float4*>(pos + (q << 6) + mt * 16 + lg * 4);
        s[mt][j][0] = s[mt][j][0] * scale + pv.x;
        s[mt][j][1] = s[mt][j][1] * scale + pv.y;
        s[mt][j][2] = s[mt][j][2] * scale + pv.z;
        s[mt][j][3] = s[mt][j][3] * scale + pv.w;
      }
      float m = s[0][j][0];
#pragma unroll
      for (int mt = 0; mt < 4; ++mt)
#pragma unroll
        for (int r = 0; r < 4; ++r) m = fmaxf(m, s[mt][j][r]);
      m = fmaxf(m, __shfl_xor(m, 16));
      m = fmaxf(m, __shfl_xor(m, 32));
      float sum = 0.f;
#pragma unroll
      for (int mt = 0; mt < 4; ++mt)
#pragma unroll
        for (int r = 0; r < 4; ++r) {
          float e = exp2f((s[mt][j][r] - m) * L2E);
          s[mt][j][r] = e;
          sum += e;
        }
      sum += __shfl_xor(sum, 16);
      sum += __shfl_xor(sum, 32);
      float rinv = __builtin_amdgcn_rcpf(sum);
#pragma unroll
      for (int mt = 0; mt < 4; ++mt) {
        float4 o;
        o.x = (s[mt][j][0] *= rinv);
        o.y = (s[mt][j][1] *= rinv);
        o.z = (s[mt][j][2] *= rinv);
        o.w = (s[mt][j][3] *= rinv);
        *reinterpret_cast<float4*>(attn_out + (q << 6) + mt * 16 + lg * 4) = o;
        P16[mt][nt][0] = (f16)s[mt][j][0];
        P16[mt][nt][1] = (f16)s[mt][j][1];
        P16[mt][nt][2] = (f16)s[mt][j][2];
        P16[mt][nt][3] = (f16)s[mt][j][3];
      }
    }
  }
  __syncthreads();  // BAR4: Xv staged; all aK/B reads done

  // ---- ph5: V projection (reads all A) ----
  f32x4 vacc[4][2];
  proj_acc(smem + R_A, Wv16, vacc, w, lr, lg);
  __syncthreads();  // BAR5: all A reads done -> V^T may overwrite A (own rows)

  // ---- ph6: V^T->A own rows; bV; P halves->B own slot (time-shared); PV; O->B ----
  {
    float c0 = bv[w * 32 + lr], c1 = bv[w * 32 + 16 + lr];
#pragma unroll
    for (int mt = 0; mt < 4; ++mt)
#pragma unroll
      for (int n = 0; n < 2; ++n) {
        int co = w * 32 + n * 16 + lr;       // feature row of V^T [128][64]
        f16x4 h;
        h[0] = (f16)(vacc[mt][n][0] + (n ? c1 : c0));
        h[1] = (f16)(vacc[mt][n][1] + (n ? c1 : c0));
        h[2] = (f16)(vacc[mt][n][2] + (n ? c1 : c0));
        h[3] = (f16)(vacc[mt][n][3] + (n ? c1 : c0));
        *reinterpret_cast<f16x4*>(smem + R_A + (co << 7) +
            (((mt << 5) + (lg << 3)) ^ ((co & 7) << 4))) = h;
      }
  }
  f16x8 bV[2][2];
#pragma unroll
  for (int n = 0; n < 2; ++n)
#pragma unroll
    for (int kt = 0; kt < 2; ++kt) {
      int d = w * 32 + n * 16 + lr;
      bV[n][kt] = *reinterpret_cast<const f16x8*>(smem + R_A + (d << 7) +
          (((kt << 6) + (lg << 4)) ^ ((d & 7) << 4)));
    }
  // P half-k -> own B slot: byte = q*256 + ((w*64 + (MT&1)*32 + lg*8) ^ swz).
  // Halves TIME-SHARE the same 64B slot: write half, consume (same addr), overwrite.
#define WR_P(MT)                                                                   \
  {                                                                                \
    _Pragma("unroll") for (int nt = 0; nt < 4; ++nt) {                             \
      const int q = nt * 16 + lr;                                                  \
      *reinterpret_cast<f16x4*>(smem + R_B + (q << 8) +                            \
          ((((w) << 6) + (((MT) & 1) << 5) + (lg << 3)) ^ ((q & 7) << 4))) =       \
          P16[MT][nt];                                                             \
    }                                                                              \
  }
  f32x4 oacc[4][2];
#pragma unroll
  for (int mt = 0; mt < 4; ++mt)
#pragma unroll
    for (int n = 0; n < 2; ++n)
      oacc[mt][n] = f32x4{0.f, 0.f, 0.f, 0.f};
  WR_P(0)
  WR_P(1)
#pragma unroll
  for (int mt = 0; mt < 4; ++mt) {   // kt = 0 (k 0..31)
    int q = mt * 16 + lr;
    f16x8 aP = *reinterpret_cast<const f16x8*>(smem + R_B + (q << 8) +
        (((w << 6) + (lg << 4)) ^ ((q & 7) << 4)));
    oacc[mt][0] = __builtin_amdgcn_mfma_f32_16x16x32_f16(aP, bV[0][0], oacc[mt][0], 0, 0, 0);
    oacc[mt][1] = __builtin_amdgcn_mfma_f32_16x16x32_f16(aP, bV[1][0], oacc[mt][1], 0, 0, 0);
  }
  WR_P(2)
  WR_P(3)
#pragma unroll
  for (int mt = 0; mt < 4; ++mt) {   // kt = 1 (k 32..63): SAME slot bytes as kt=0
    int q = mt * 16 + lr;
    f16x8 aP = *reinterpret_cast<const f16x8*>(smem + R_B + (q << 8) +
        (((w << 6) + (lg << 4)) ^ ((q & 7) << 4)));
    oacc[mt][0] = __builtin_amdgcn_mfma_f32_16x16x32_f16(aP, bV[0][1], oacc[mt][0], 0, 0, 0);
    oacc[mt][1] = __builtin_amdgcn_mfma_f32_16x16x32_f16(aP, bV[1][1], oacc[mt][1], 0, 0, 0);
  }
  // O (merged heads) -> B own cols (over own P slot; own aP reads are done)
  epi_rowmajor(oacc, smem + R_B, nullptr, w, lr, lg);
  __syncthreads();  // BAR6: all O cols written

  // ---- ph7: x = O @ Wp^T + bp -> global fp32 ----
  f32x4 xacc[4][2];
  proj_acc(smem + R_B, Wp16, xacc, w, lr, lg);
  const float b0 = bp[w * 32 + lr];
  const float b1 = bp[w * 32 + 16 + lr];
  float* xo = d_x + winOff;
#pragma unroll
  for (int mt = 0; mt < 4; ++mt)
#pragma unroll
    for (int n = 0; n < 2; ++n)
#pragma unroll
      for (int r = 0; r < 4; ++r) {
        int row = mt * 16 + lg * 4 + r;
        int col = w * 32 + n * 16 + lr;
        xo[(row << 7) + col] = xacc[mt][n][r] + (n ? b1 : b0);
      }
}

extern "C" void kernel_launch(void* const* d_in, const int* in_sizes, int n_in,
                              void* d_out, int out_size, void* d_ws, size_t ws_size,
                              hipStream_t stream) {
  const float* q   = (const float*)d_in[0];
  const float* k   = (const float*)d_in[1];
  const float* v   = (const float*)d_in[2];
  const float* pos = (const float*)d_in[3];
  const float* Wq  = (const float*)d_in[4];
  const float* bq  = (const float*)d_in[5];
  const float* Wk  = (const float*)d_in[6];
  const float* Wv  = (const float*)d_in[7];
  const float* bv  = (const float*)d_in[8];
  const float* Wp  = (const float*)d_in[9];
  const float* bp  = (const float*)d_in[10];
  const float* ls  = (const float*)d_in[11];
  f16* W16 = (f16*)d_ws;   // 4 x 128 x 128 f16 = 128KB
  float* d_x    = (float*)d_out;
  float* d_attn = d_x + (size_t)16 * 16 * 16 * 64 * 128;  // 33,554,432
  wcvt_kernel<<<64, 256, 0, stream>>>(Wq, Wk, Wv, Wp, W16);
  fpca_kernel<<<4096, 256, 0, stream>>>(q, k, v, pos, W16, bq, bv, bp, ls,
                                        d_x, d_attn);
}

// Round 9
// 212.471 us; speedup vs baseline: 1.7487x; 1.7487x over previous
//
#include <hip/hip_runtime.h>

using f16   = _Float16;
using f16x4 = __attribute__((ext_vector_type(4))) _Float16;
using f16x8 = __attribute__((ext_vector_type(8))) _Float16;
using f32x4 = __attribute__((ext_vector_type(4))) float;

#define DEVI __device__ __forceinline__

namespace {
// 80KB LDS: three staged inputs (shared, read-only after BAR1) + per-wave scratch.
//  S_XQ: Xq [64][128] f16 swzA   (becomes O after BAR2)
//  S_XK: Xk [64][128] f16 swzA
//  S_XV: Xv [64][128] f16 swzA
//  S_SCR + w*8192: wave-private scratch, time-multiplexed:
//     {Q [64][32] @0, K [64][32] @4K} -> P [64][64] (128B rows) -> V^T [32][64] @0
constexpr int S_XQ  = 0;
constexpr int S_XK  = 16384;
constexpr int S_XV  = 32768;
constexpr int S_SCR = 49152;
constexpr float LOGIT_MAX_C = 4.6051701859880914f;  // log(100)
constexpr float L2E = 1.4426950408889634f;
}

// XOR swizzles. Masks touch only bits >=4 so 16B-aligned vector reads map to
// 16B-aligned blocks with byte order preserved (bit-3 masks break this — R8 bug).
DEVI int swzA(int row, int b) { return (row << 8) + (b ^ ((row & 7) << 4)); }   // 256B rows
DEVI int swz64(int row, int b) { return (row << 6) + (b ^ (((row >> 1) & 3) << 4)); }  // 64B rows

DEVI f16x8 ldA(const char* base, int row, int k0) {   // [*,128] f16 tile, b128
  return *reinterpret_cast<const f16x8*>(base + swzA(row, k0 << 1));
}

// Stage one 64x128 fp32 tile -> f16 swizzled LDS tile (coalesced float4 loads)
DEVI void stage_in(const float* __restrict__ src, char* __restrict__ dst, int tid) {
#pragma unroll
  for (int i = 0; i < 8; ++i) {
    int f = tid + (i << 8);
    float4 v = reinterpret_cast<const float4*>(src)[f];
    f16x4 h;
    h[0] = (f16)v.x; h[1] = (f16)v.y; h[2] = (f16)v.z; h[3] = (f16)v.w;
    *reinterpret_cast<f16x4*>(dst + swzA(f >> 5, (f & 31) << 3)) = h;
  }
}

// X(lds) @ W^T accumulate (W fragments loaded per-kt from L2-resident f16 table).
DEVI void proj_acc(const char* __restrict__ xb, const f16* __restrict__ Wm,
                   f32x4 (&acc)[4][2], int w, int lr, int lg) {
#pragma unroll
  for (int mt = 0; mt < 4; ++mt)
#pragma unroll
    for (int n = 0; n < 2; ++n)
      acc[mt][n] = f32x4{0.f, 0.f, 0.f, 0.f};
#pragma unroll
  for (int kt = 0; kt < 4; ++kt) {
    f16x8 b0 = *reinterpret_cast<const f16x8*>(Wm + (w * 32 + lr) * 128 + kt * 32 + lg * 8);
    f16x8 b1 = *reinterpret_cast<const f16x8*>(Wm + (w * 32 + 16 + lr) * 128 + kt * 32 + lg * 8);
#pragma unroll
    for (int mt = 0; mt < 4; ++mt) {
      f16x8 a = ldA(xb, mt * 16 + lr, kt * 32 + lg * 8);
      acc[mt][0] = __builtin_amdgcn_mfma_f32_16x16x32_f16(a, b0, acc[mt][0], 0, 0, 0);
      acc[mt][1] = __builtin_amdgcn_mfma_f32_16x16x32_f16(a, b1, acc[mt][1], 0, 0, 0);
    }
  }
}

// C/D -> wave-private [64 rows][32 cols] f16 scratch (64B rows, swz64).
DEVI void epi_scr64(const f32x4 (&acc)[4][2], char* __restrict__ scr,
                    const float* __restrict__ bias, int lr, int lg) {
  float b0 = bias ? bias[lr] : 0.f;
  float b1 = bias ? bias[16 + lr] : 0.f;
#pragma unroll
  for (int mt = 0; mt < 4; ++mt)
#pragma unroll
    for (int n = 0; n < 2; ++n)
#pragma unroll
      for (int r = 0; r < 4; ++r) {
        int row = mt * 16 + lg * 4 + r;
        *reinterpret_cast<f16*>(scr + swz64(row, (n * 16 + lr) << 1)) =
            (f16)(acc[mt][n][r] + (n ? b1 : b0));
      }
}
// fragment read from 64B-row scratch: row-major, features lg*8..+8 (16B)
DEVI f16x8 ldS64(const char* __restrict__ scr, int row, int lg) {
  return *reinterpret_cast<const f16x8*>(scr + swz64(row, lg << 4));
}

// C/D (col=lane&15, row=(lane>>4)*4+r) -> shared row-major [64][128] f16, own cols.
DEVI void epi_rowmajor(const f32x4 (&acc)[4][2], char* __restrict__ dst,
                       int w, int lr, int lg) {
#pragma unroll
  for (int mt = 0; mt < 4; ++mt)
#pragma unroll
    for (int n = 0; n < 2; ++n)
#pragma unroll
      for (int r = 0; r < 4; ++r) {
        int row = mt * 16 + lg * 4 + r;
        int col = w * 32 + n * 16 + lr;
        *reinterpret_cast<f16*>(dst + swzA(row, col << 1)) = (f16)acc[mt][n][r];
      }
}

// fp32 weights -> f16 workspace (Wq,Wk,Wv,Wp)
__global__ void wcvt_kernel(const float* __restrict__ Wq, const float* __restrict__ Wk,
                            const float* __restrict__ Wv, const float* __restrict__ Wp,
                            f16* __restrict__ W16) {
  int idx = blockIdx.x * 256 + threadIdx.x;   // 0..16383
  int m = idx >> 12;
  int off = (idx & 4095) << 2;
  const float* src = m == 0 ? Wq : m == 1 ? Wk : m == 2 ? Wv : Wp;
  float4 v = *reinterpret_cast<const float4*>(src + off);
  f16x4 h;
  h[0] = (f16)v.x; h[1] = (f16)v.y; h[2] = (f16)v.z; h[3] = (f16)v.w;
  *reinterpret_cast<f16x4*>(W16 + (m << 14) + off) = h;
}

__global__ __launch_bounds__(256, 2)
void fpca_kernel(const float* __restrict__ q_in, const float* __restrict__ k_in,
                 const float* __restrict__ v_in, const float* __restrict__ pos_in,
                 const f16* __restrict__ W16,
                 const float* __restrict__ bq, const float* __restrict__ bv,
                 const float* __restrict__ bp, const float* __restrict__ lsc,
                 float* __restrict__ d_x, float* __restrict__ d_attn) {
  __shared__ char smem[81920];
  const int tid = threadIdx.x;
  const int w = tid >> 6;        // wave id == head id
  const int lane = tid & 63;
  const int lr = lane & 15;
  const int lg = lane >> 4;
  const int win = blockIdx.x;
  const int b = win >> 8;
  const size_t winOff = (size_t)win << 13;
  const f16* Wq16 = W16;
  const f16* Wk16 = W16 + 16384;
  const f16* Wv16 = W16 + 32768;
  const f16* Wp16 = W16 + 49152;
  char* scr = smem + S_SCR + (w << 13);   // 8KB wave-private scratch

  // ---- stage all three inputs (only block-wide cooperative phase) ----
  stage_in(q_in + winOff, smem + S_XQ, tid);
  stage_in(k_in + winOff, smem + S_XK, tid);
  stage_in(v_in + winOff, smem + S_XV, tid);
  __syncthreads();  // BAR1: stage regions valid & read-only until BAR2

  // ================= wave-private free-running section =================
  // ---- Q projection -> scratch@0 -> bQ; K projection -> scratch@4K -> aK ----
  f32x4 acc[4][2];
  proj_acc(smem + S_XQ, Wq16, acc, w, lr, lg);
  epi_scr64(acc, scr, bq + w * 32, lr, lg);
  f16x8 bQ[4];
#pragma unroll
  for (int nt = 0; nt < 4; ++nt) bQ[nt] = ldS64(scr, nt * 16 + lr, lg);

  proj_acc(smem + S_XK, Wk16, acc, w, lr, lg);
  epi_scr64(acc, scr + 4096, nullptr, lr, lg);
  f16x8 aK[4];
#pragma unroll
  for (int mt = 0; mt < 4; ++mt) aK[mt] = ldS64(scr + 4096, mt * 16 + lr, lg);

  // ---- S^T = K Q^T, + scale/pos, softmax per q-column, attn out, P16 pack ----
  const float scale = exp2f(fminf(lsc[w], LOGIT_MAX_C) * L2E);
  const float* pos = pos_in + (((size_t)b * 4 + w) << 12);
  float* attn_out = d_attn + (((size_t)win * 4 + w) << 12);
  f16x4 P16[4][4];
#pragma unroll
  for (int nt = 0; nt < 4; ++nt) {
    f32x4 s[4];
#pragma unroll
    for (int mt = 0; mt < 4; ++mt) s[mt] = f32x4{0.f, 0.f, 0.f, 0.f};
#pragma unroll
    for (int mt = 0; mt < 4; ++mt)
      s[mt] = __builtin_amdgcn_mfma_f32_16x16x32_f16(aK[mt], bQ[nt], s[mt], 0, 0, 0);
    const int q = nt * 16 + lr;   // lane's q-col; k = mt*16+lg*4+r (lane-local)
#pragma unroll
    for (int mt = 0; mt < 4; ++mt) {
      float4 pv = *reinterpret_cast<const float4*>(pos + (q << 6) + mt * 16 + lg * 4);
      s[mt][0] = s[mt][0] * scale + pv.x;
      s[mt][1] = s[mt][1] * scale + pv.y;
      s[mt][2] = s[mt][2] * scale + pv.z;
      s[mt][3] = s[mt][3] * scale + pv.w;
    }
    float m = s[0][0];
#pragma unroll
    for (int mt = 0; mt < 4; ++mt)
#pragma unroll
      for (int r = 0; r < 4; ++r) m = fmaxf(m, s[mt][r]);
    m = fmaxf(m, __shfl_xor(m, 16));
    m = fmaxf(m, __shfl_xor(m, 32));
    float sum = 0.f;
#pragma unroll
    for (int mt = 0; mt < 4; ++mt)
#pragma unroll
      for (int r = 0; r < 4; ++r) {
        float e = exp2f((s[mt][r] - m) * L2E);
        s[mt][r] = e;
        sum += e;
      }
    sum += __shfl_xor(sum, 16);
    sum += __shfl_xor(sum, 32);
    float rinv = __builtin_amdgcn_rcpf(sum);
#pragma unroll
    for (int mt = 0; mt < 4; ++mt) {
      float4 o;
      o.x = (s[mt][0] *= rinv);
      o.y = (s[mt][1] *= rinv);
      o.z = (s[mt][2] *= rinv);
      o.w = (s[mt][3] *= rinv);
      *reinterpret_cast<float4*>(attn_out + (q << 6) + mt * 16 + lg * 4) = o;
      P16[mt][nt][0] = (f16)s[mt][0];
      P16[mt][nt][1] = (f16)s[mt][1];
      P16[mt][nt][2] = (f16)s[mt][2];
      P16[mt][nt][3] = (f16)s[mt][3];
    }
  }

  // ---- P -> scratch [64 q][64 k] (128B rows; Q/K dead) -> aP fragments ----
#pragma unroll
  for (int mt = 0; mt < 4; ++mt)
#pragma unroll
    for (int nt = 0; nt < 4; ++nt) {
      const int q = nt * 16 + lr;
      *reinterpret_cast<f16x4*>(scr + (q << 7) +
          ((mt * 32 + lg * 8) ^ ((lr & 7) << 4))) = P16[mt][nt];
    }
  f16x8 aP[4][2];
#pragma unroll
  for (int mt = 0; mt < 4; ++mt)
#pragma unroll
    for (int kt = 0; kt < 2; ++kt) {
      const int q = mt * 16 + lr;
      aP[mt][kt] = *reinterpret_cast<const f16x8*>(scr + (q << 7) +
          ((kt * 64 + lg * 16) ^ ((lr & 7) << 4)));
    }

  // ---- V projection (last read of stage regions) -> V^T scratch@0 -> bV ----
  proj_acc(smem + S_XV, Wv16, acc, w, lr, lg);
  {
    float c0 = bv[w * 32 + lr], c1 = bv[w * 32 + 16 + lr];
#pragma unroll
    for (int mt = 0; mt < 4; ++mt)
#pragma unroll
      for (int n = 0; n < 2; ++n) {
        int co = n * 16 + lr;                // local feature row of V^T [32][64]
        f16x4 h;
        h[0] = (f16)(acc[mt][n][0] + (n ? c1 : c0));
        h[1] = (f16)(acc[mt][n][1] + (n ? c1 : c0));
        h[2] = (f16)(acc[mt][n][2] + (n ? c1 : c0));
        h[3] = (f16)(acc[mt][n][3] + (n ? c1 : c0));
        *reinterpret_cast<f16x4*>(scr + (co << 7) +
            ((mt * 32 + lg * 8) ^ ((lr & 7) << 4))) = h;
      }
  }
  f16x8 bV[2][2];
#pragma unroll
  for (int n = 0; n < 2; ++n)
#pragma unroll
    for (int kt = 0; kt < 2; ++kt) {
      int d = n * 16 + lr;
      bV[n][kt] = *reinterpret_cast<const f16x8*>(scr + (d << 7) +
          ((kt * 64 + lg * 16) ^ ((lr & 7) << 4)));
    }

  // ---- O_h = P @ V_h ----
  f32x4 oacc[4][2];
#pragma unroll
  for (int mt = 0; mt < 4; ++mt)
#pragma unroll
    for (int n = 0; n < 2; ++n)
      oacc[mt][n] = f32x4{0.f, 0.f, 0.f, 0.f};
#pragma unroll
  for (int mt = 0; mt < 4; ++mt)
#pragma unroll
    for (int kt = 0; kt < 2; ++kt) {
      oacc[mt][0] = __builtin_amdgcn_mfma_f32_16x16x32_f16(aP[mt][kt], bV[0][kt], oacc[mt][0], 0, 0, 0);
      oacc[mt][1] = __builtin_amdgcn_mfma_f32_16x16x32_f16(aP[mt][kt], bV[1][kt], oacc[mt][1], 0, 0, 0);
    }
  // ================= end wave-private section =================

  __syncthreads();  // BAR2: every wave past projV -> stage regions all dead
  // ---- O (merged heads) -> S_XQ region, own cols ----
  epi_rowmajor(oacc, smem + S_XQ, w, lr, lg);
  __syncthreads();  // BAR3: O complete

  // ---- x = O @ Wp^T + bp -> global fp32 ----
  f32x4 xacc[4][2];
  proj_acc(smem + S_XQ, Wp16, xacc, w, lr, lg);
  const float b0 = bp[w * 32 + lr];
  const float b1 = bp[w * 32 + 16 + lr];
  float* xo = d_x + winOff;
#pragma unroll
  for (int mt = 0; mt < 4; ++mt)
#pragma unroll
    for (int n = 0; n < 2; ++n)
#pragma unroll
      for (int r = 0; r < 4; ++r) {
        int row = mt * 16 + lg * 4 + r;
        int col = w * 32 + n * 16 + lr;
        xo[(row << 7) + col] = xacc[mt][n][r] + (n ? b1 : b0);
      }
}

extern "C" void kernel_launch(void* const* d_in, const int* in_sizes, int n_in,
                              void* d_out, int out_size, void* d_ws, size_t ws_size,
                              hipStream_t stream) {
  const float* q   = (const float*)d_in[0];
  const float* k   = (const float*)d_in[1];
  const float* v   = (const float*)d_in[2];
  const float* pos = (const float*)d_in[3];
  const float* Wq  = (const float*)d_in[4];
  const float* bq  = (const float*)d_in[5];
  const float* Wk  = (const float*)d_in[6];
  const float* Wv  = (const float*)d_in[7];
  const float* bv  = (const float*)d_in[8];
  const float* Wp  = (const float*)d_in[9];
  const float* bp  = (const float*)d_in[10];
  const float* ls  = (const float*)d_in[11];
  f16* W16 = (f16*)d_ws;   // 4 x 128 x 128 f16 = 128KB
  float* d_x    = (float*)d_out;
  float* d_attn = d_x + (size_t)16 * 16 * 16 * 64 * 128;  // 33,554,432
  wcvt_kernel<<<64, 256, 0, stream>>>(Wq, Wk, Wv, Wp, W16);
  fpca_kernel<<<4096, 256, 0, stream>>>(q, k, v, pos, W16, bq, bv, bp, ls,
                                        d_x, d_attn);
}

// Round 10
// 205.553 us; speedup vs baseline: 1.8076x; 1.0337x over previous
//
#include <hip/hip_runtime.h>

using f16   = _Float16;
using f16x4 = __attribute__((ext_vector_type(4))) _Float16;
using f16x8 = __attribute__((ext_vector_type(8))) _Float16;
using f32x4 = __attribute__((ext_vector_type(4))) float;

#define DEVI __device__ __forceinline__

namespace {
// 48KB LDS:
//  S_XQ @0    : Xq [64][128] f16 swzA (all-wave read) -> O (own cols) after BAR2
//  S_XK @16K  : Xk [64][128] f16 swzA -> Xv (written after BAR2, read after BAR3)
//  S_SCR @32K : 4KB per-wave scratch, time-multiplexed (same-wave ordering):
//               Q [64][32] -> K [64][32] -> P k-halves [64][32] x2 -> V^T [32][64]
constexpr int S_XQ  = 0;
constexpr int S_XK  = 16384;
constexpr int S_SCR = 32768;
constexpr float LOGIT_MAX_C = 4.6051701859880914f;  // log(100)
constexpr float L2E = 1.4426950408889634f;
}

// XOR swizzles. Masks only touch bits >=4 so 16B-aligned vector reads stay
// 16B-block-aligned with byte order preserved (bit-3 masks corrupt — R8 bug).
DEVI int swzA(int row, int b) { return (row << 8) + (b ^ ((row & 7) << 4)); }   // 256B rows
DEVI int swz64(int row, int b) { return (row << 6) + (b ^ (((row >> 1) & 3) << 4)); }  // 64B rows

DEVI f16x8 ldA(const char* base, int row, int k0) {   // [*,128] f16 tile, b128
  return *reinterpret_cast<const f16x8*>(base + swzA(row, k0 << 1));
}

// Stage one 64x128 fp32 tile -> f16 swizzled LDS tile (coalesced float4 loads)
DEVI void stage_in(const float* __restrict__ src, char* __restrict__ dst, int tid) {
#pragma unroll
  for (int i = 0; i < 8; ++i) {
    int f = tid + (i << 8);
    float4 v = reinterpret_cast<const float4*>(src)[f];
    f16x4 h;
    h[0] = (f16)v.x; h[1] = (f16)v.y; h[2] = (f16)v.z; h[3] = (f16)v.w;
    *reinterpret_cast<f16x4*>(dst + swzA(f >> 5, (f & 31) << 3)) = h;
  }
}

// X(lds) @ W^T accumulate (W fragments loaded per-kt from L2-resident f16 table).
DEVI void proj_acc(const char* __restrict__ xb, const f16* __restrict__ Wm,
                   f32x4 (&acc)[4][2], int w, int lr, int lg) {
#pragma unroll
  for (int mt = 0; mt < 4; ++mt)
#pragma unroll
    for (int n = 0; n < 2; ++n)
      acc[mt][n] = f32x4{0.f, 0.f, 0.f, 0.f};
#pragma unroll
  for (int kt = 0; kt < 4; ++kt) {
    f16x8 b0 = *reinterpret_cast<const f16x8*>(Wm + (w * 32 + lr) * 128 + kt * 32 + lg * 8);
    f16x8 b1 = *reinterpret_cast<const f16x8*>(Wm + (w * 32 + 16 + lr) * 128 + kt * 32 + lg * 8);
#pragma unroll
    for (int mt = 0; mt < 4; ++mt) {
      f16x8 a = ldA(xb, mt * 16 + lr, kt * 32 + lg * 8);
      acc[mt][0] = __builtin_amdgcn_mfma_f32_16x16x32_f16(a, b0, acc[mt][0], 0, 0, 0);
      acc[mt][1] = __builtin_amdgcn_mfma_f32_16x16x32_f16(a, b1, acc[mt][1], 0, 0, 0);
    }
  }
}

// C/D -> wave-private [64 rows][32 cols] f16 scratch (64B rows, swz64).
DEVI void epi_scr64(const f32x4 (&acc)[4][2], char* __restrict__ scr,
                    const float* __restrict__ bias, int lr, int lg) {
  float b0 = bias ? bias[lr] : 0.f;
  float b1 = bias ? bias[16 + lr] : 0.f;
#pragma unroll
  for (int mt = 0; mt < 4; ++mt)
#pragma unroll
    for (int n = 0; n < 2; ++n)
#pragma unroll
      for (int r = 0; r < 4; ++r) {
        int row = mt * 16 + lg * 4 + r;
        *reinterpret_cast<f16*>(scr + swz64(row, (n * 16 + lr) << 1)) =
            (f16)(acc[mt][n][r] + (n ? b1 : b0));
      }
}
// fragment read from 64B-row scratch: row-major, features lg*8..+8 (16B)
DEVI f16x8 ldS64(const char* __restrict__ scr, int row, int lg) {
  return *reinterpret_cast<const f16x8*>(scr + swz64(row, lg << 4));
}

// C/D (col=lane&15, row=(lane>>4)*4+r) -> shared row-major [64][128] f16, own cols.
DEVI void epi_rowmajor(const f32x4 (&acc)[4][2], char* __restrict__ dst,
                       int w, int lr, int lg) {
#pragma unroll
  for (int mt = 0; mt < 4; ++mt)
#pragma unroll
    for (int n = 0; n < 2; ++n)
#pragma unroll
      for (int r = 0; r < 4; ++r) {
        int row = mt * 16 + lg * 4 + r;
        int col = w * 32 + n * 16 + lr;
        *reinterpret_cast<f16*>(dst + swzA(row, col << 1)) = (f16)acc[mt][n][r];
      }
}

// fp32 weights -> f16 workspace (Wq,Wk,Wv,Wp)
__global__ void wcvt_kernel(const float* __restrict__ Wq, const float* __restrict__ Wk,
                            const float* __restrict__ Wv, const float* __restrict__ Wp,
                            f16* __restrict__ W16) {
  int idx = blockIdx.x * 256 + threadIdx.x;   // 0..16383
  int m = idx >> 12;
  int off = (idx & 4095) << 2;
  const float* src = m == 0 ? Wq : m == 1 ? Wk : m == 2 ? Wv : Wp;
  float4 v = *reinterpret_cast<const float4*>(src + off);
  f16x4 h;
  h[0] = (f16)v.x; h[1] = (f16)v.y; h[2] = (f16)v.z; h[3] = (f16)v.w;
  *reinterpret_cast<f16x4*>(W16 + (m << 14) + off) = h;
}

__global__ __launch_bounds__(256, 3)
void fpca_kernel(const float* __restrict__ q_in, const float* __restrict__ k_in,
                 const float* __restrict__ v_in, const float* __restrict__ pos_in,
                 const f16* __restrict__ W16,
                 const float* __restrict__ bq, const float* __restrict__ bv,
                 const float* __restrict__ bp, const float* __restrict__ lsc,
                 float* __restrict__ d_x, float* __restrict__ d_attn) {
  __shared__ char smem[49152];
  const int tid = threadIdx.x;
  const int w = tid >> 6;        // wave id == head id
  const int lane = tid & 63;
  const int lr = lane & 15;
  const int lg = lane >> 4;
  const int win = blockIdx.x;
  const int b = win >> 8;
  const size_t winOff = (size_t)win << 13;
  const f16* Wq16 = W16;
  const f16* Wk16 = W16 + 16384;
  const f16* Wv16 = W16 + 32768;
  const f16* Wp16 = W16 + 49152;
  char* scr = smem + S_SCR + (w << 12);   // 4KB wave-private scratch

  // ---- ph1: stage Xq->S_XQ, Xk->S_XK; prefetch Xv into f16 regs ----
  stage_in(q_in + winOff, smem + S_XQ, tid);
  stage_in(k_in + winOff, smem + S_XK, tid);
  const float4* vsrc = reinterpret_cast<const float4*>(v_in + winOff);
  f16x4 pfh[8];
#pragma unroll
  for (int i = 0; i < 8; ++i) {
    float4 v = vsrc[tid + (i << 8)];
    pfh[i][0] = (f16)v.x; pfh[i][1] = (f16)v.y;
    pfh[i][2] = (f16)v.z; pfh[i][3] = (f16)v.w;
  }
  __syncthreads();  // BAR1: stage regions valid

  // ---- Q projection -> scr -> bQ; K projection -> scr (Q dead) -> aK ----
  f32x4 acc[4][2];
  proj_acc(smem + S_XQ, Wq16, acc, w, lr, lg);
  epi_scr64(acc, scr, bq + w * 32, lr, lg);
  f16x8 bQ[4];
#pragma unroll
  for (int nt = 0; nt < 4; ++nt) bQ[nt] = ldS64(scr, nt * 16 + lr, lg);

  proj_acc(smem + S_XK, Wk16, acc, w, lr, lg);
  epi_scr64(acc, scr, nullptr, lr, lg);
  f16x8 aK[4];
#pragma unroll
  for (int mt = 0; mt < 4; ++mt) aK[mt] = ldS64(scr, mt * 16 + lr, lg);
  __syncthreads();  // BAR2: all waves done reading S_XQ/S_XK

  // ---- Xv regs -> S_XK (stage slot reuse) ----
#pragma unroll
  for (int i = 0; i < 8; ++i) {
    int f = tid + (i << 8);
    *reinterpret_cast<f16x4*>(smem + S_XK + swzA(f >> 5, (f & 31) << 3)) = pfh[i];
  }

  // ---- S^T = K Q^T, + scale/pos, softmax per q-column, attn out, P16 pack ----
  const float scale = exp2f(fminf(lsc[w], LOGIT_MAX_C) * L2E);
  const float* pos = pos_in + (((size_t)b * 4 + w) << 12);
  float* attn_out = d_attn + (((size_t)win * 4 + w) << 12);
  f16x4 P16[4][4];
#pragma unroll
  for (int nt = 0; nt < 4; ++nt) {
    f32x4 s[4];
#pragma unroll
    for (int mt = 0; mt < 4; ++mt) s[mt] = f32x4{0.f, 0.f, 0.f, 0.f};
#pragma unroll
    for (int mt = 0; mt < 4; ++mt)
      s[mt] = __builtin_amdgcn_mfma_f32_16x16x32_f16(aK[mt], bQ[nt], s[mt], 0, 0, 0);
    const int q = nt * 16 + lr;   // lane's q-col; k = mt*16+lg*4+r (lane-local)
#pragma unroll
    for (int mt = 0; mt < 4; ++mt) {
      float4 pv = *reinterpret_cast<const float4*>(pos + (q << 6) + mt * 16 + lg * 4);
      s[mt][0] = s[mt][0] * scale + pv.x;
      s[mt][1] = s[mt][1] * scale + pv.y;
      s[mt][2] = s[mt][2] * scale + pv.z;
      s[mt][3] = s[mt][3] * scale + pv.w;
    }
    float m = s[0][0];
#pragma unroll
    for (int mt = 0; mt < 4; ++mt)
#pragma unroll
      for (int r = 0; r < 4; ++r) m = fmaxf(m, s[mt][r]);
    m = fmaxf(m, __shfl_xor(m, 16));
    m = fmaxf(m, __shfl_xor(m, 32));
    float sum = 0.f;
#pragma unroll
    for (int mt = 0; mt < 4; ++mt)
#pragma unroll
      for (int r = 0; r < 4; ++r) {
        float e = exp2f((s[mt][r] - m) * L2E);
        s[mt][r] = e;
        sum += e;
      }
    sum += __shfl_xor(sum, 16);
    sum += __shfl_xor(sum, 32);
    float rinv = __builtin_amdgcn_rcpf(sum);
#pragma unroll
    for (int mt = 0; mt < 4; ++mt) {
      float4 o;
      o.x = (s[mt][0] *= rinv);
      o.y = (s[mt][1] *= rinv);
      o.z = (s[mt][2] *= rinv);
      o.w = (s[mt][3] *= rinv);
      *reinterpret_cast<float4*>(attn_out + (q << 6) + mt * 16 + lg * 4) = o;
      P16[mt][nt][0] = (f16)s[mt][0];
      P16[mt][nt][1] = (f16)s[mt][1];
      P16[mt][nt][2] = (f16)s[mt][2];
      P16[mt][nt][3] = (f16)s[mt][3];
    }
  }

  // ---- P k-halves -> scr [64 q][32 k] (time-shared, K dead) -> aP hoist ----
  // local k' = (MT&1)*16 + lg*4 + r -> byte (MT&1)*32 + lg*8 (+2r); 64B rows,
  // mask bits 4..5 only (16B-block aligned).
#define WR_P(MT)                                                                   \
  {                                                                                \
    _Pragma("unroll") for (int nt = 0; nt < 4; ++nt) {                             \
      const int q = nt * 16 + lr;                                                  \
      *reinterpret_cast<f16x4*>(scr + (q << 6) +                                   \
          (((((MT) & 1) << 5) + (lg << 3)) ^ (((q >> 1) & 3) << 4))) =             \
          P16[MT][nt];                                                             \
    }                                                                              \
  }
  f16x8 aP[4][2];
#pragma unroll
  for (int h = 0; h < 2; ++h) {
    WR_P(2 * h)
    WR_P(2 * h + 1)
#pragma unroll
    for (int mt = 0; mt < 4; ++mt) {
      const int q = mt * 16 + lr;
      aP[mt][h] = *reinterpret_cast<const f16x8*>(scr + (q << 6) +
          ((lg << 4) ^ (((q >> 1) & 3) << 4)));
    }
  }
  __syncthreads();  // BAR3: Xv staged complete (and all waves past QK phase)

  // ---- V projection (reads S_XK = Xv) -> V^T scr [32][64] (P dead) -> bV ----
  proj_acc(smem + S_XK, Wv16, acc, w, lr, lg);
  {
    float c0 = bv[w * 32 + lr], c1 = bv[w * 32 + 16 + lr];
#pragma unroll
    for (int mt = 0; mt < 4; ++mt)
#pragma unroll
      for (int n = 0; n < 2; ++n) {
        int d = n * 16 + lr;                 // local feature row of V^T [32][64]
        f16x4 h;
        h[0] = (f16)(acc[mt][n][0] + (n ? c1 : c0));
        h[1] = (f16)(acc[mt][n][1] + (n ? c1 : c0));
        h[2] = (f16)(acc[mt][n][2] + (n ? c1 : c0));
        h[3] = (f16)(acc[mt][n][3] + (n ? c1 : c0));
        *reinterpret_cast<f16x4*>(scr + (d << 7) +
            ((mt * 32 + lg * 8) ^ ((d & 7) << 4))) = h;
      }
  }
  f16x8 bV[2][2];
#pragma unroll
  for (int n = 0; n < 2; ++n)
#pragma unroll
    for (int kt = 0; kt < 2; ++kt) {
      int d = n * 16 + lr;
      bV[n][kt] = *reinterpret_cast<const f16x8*>(scr + (d << 7) +
          ((kt * 64 + lg * 16) ^ ((d & 7) << 4)));
    }

  // ---- O_h = P @ V_h ----
  f32x4 oacc[4][2];
#pragma unroll
  for (int mt = 0; mt < 4; ++mt)
#pragma unroll
    for (int n = 0; n < 2; ++n)
      oacc[mt][n] = f32x4{0.f, 0.f, 0.f, 0.f};
#pragma unroll
  for (int mt = 0; mt < 4; ++mt)
#pragma unroll
    for (int kt = 0; kt < 2; ++kt) {
      oacc[mt][0] = __builtin_amdgcn_mfma_f32_16x16x32_f16(aP[mt][kt], bV[0][kt], oacc[mt][0], 0, 0, 0);
      oacc[mt][1] = __builtin_amdgcn_mfma_f32_16x16x32_f16(aP[mt][kt], bV[1][kt], oacc[mt][1], 0, 0, 0);
    }

  // ---- O (merged heads) -> S_XQ own cols (S_XQ reads ended at BAR2) ----
  epi_rowmajor(oacc, smem + S_XQ, w, lr, lg);
  __syncthreads();  // BAR4: all O cols written

  // ---- x = O @ Wp^T + bp -> global fp32 ----
  f32x4 xacc[4][2];
  proj_acc(smem + S_XQ, Wp16, xacc, w, lr, lg);
  const float b0 = bp[w * 32 + lr];
  const float b1 = bp[w * 32 + 16 + lr];
  float* xo = d_x + winOff;
#pragma unroll
  for (int mt = 0; mt < 4; ++mt)
#pragma unroll
    for (int n = 0; n < 2; ++n)
#pragma unroll
      for (int r = 0; r < 4; ++r) {
        int row = mt * 16 + lg * 4 + r;
        int col = w * 32 + n * 16 + lr;
        xo[(row << 7) + col] = xacc[mt][n][r] + (n ? b1 : b0);
      }
}

extern "C" void kernel_launch(void* const* d_in, const int* in_sizes, int n_in,
                              void* d_out, int out_size, void* d_ws, size_t ws_size,
                              hipStream_t stream) {
  const float* q   = (const float*)d_in[0];
  const float* k   = (const float*)d_in[1];
  const float* v   = (const float*)d_in[2];
  const float* pos = (const float*)d_in[3];
  const float* Wq  = (const float*)d_in[4];
  const float* bq  = (const float*)d_in[5];
  const float* Wk  = (const float*)d_in[6];
  const float* Wv  = (const float*)d_in[7];
  const float* bv  = (const float*)d_in[8];
  const float* Wp  = (const float*)d_in[9];
  const float* bp  = (const float*)d_in[10];
  const float* ls  = (const float*)d_in[11];
  f16* W16 = (f16*)d_ws;   // 4 x 128 x 128 f16 = 128KB
  float* d_x    = (float*)d_out;
  float* d_attn = d_x + (size_t)16 * 16 * 16 * 64 * 128;  // 33,554,432
  wcvt_kernel<<<64, 256, 0, stream>>>(Wq, Wk, Wv, Wp, W16);
  fpca_kernel<<<4096, 256, 0, stream>>>(q, k, v, pos, W16, bq, bv, bp, ls,
                                        d_x, d_attn);
}